// Round 8
// baseline (24999.466 us; speedup 1.0000x reference)
//
#include <hip/hip_runtime.h>
#include <hip/hip_bf16.h>
#include <math.h>

// ---------------- problem constants ----------------
#define S_LEN 2048
#define T_LEN 2048
#define HID   1024
#define GATES 4096
#define VOCAB 50257
#define RDEPTH 64            // ring depth (steps) per stream per XCD
#define SPINCAP 65536        // hard bound on every spin loop: terminate, never wedge

typedef unsigned int u32;
typedef unsigned long long ull;
typedef u32 u32x4 __attribute__((ext_vector_type(4)));
typedef float f32x4 __attribute__((ext_vector_type(4)));

__device__ __forceinline__ float fsig_(float x)  { return 1.0f / (1.0f + __expf(-x)); }
__device__ __forceinline__ float ftanh_(float x) { float e = __expf(2.0f * x); return 1.0f - 2.0f / (e + 1.0f); }

// device-coherent 16B load: bypass L1+L2, served at the coherence point (fabric)
__device__ __forceinline__ u32x4 cload16_dev(const ull* p) {
  u32x4 v;
  asm volatile("global_load_dwordx4 %0, %1, off sc0 sc1\n\ts_waitcnt vmcnt(0)"
               : "=v"(v) : "v"(p) : "memory");
  return v;
}
// XCD-local 16B load: bypass L1 only; served by this XCD's L2 (cheap poll)
__device__ __forceinline__ u32x4 cload16_l2(const ull* p) {
  u32x4 v;
  asm volatile("global_load_dwordx4 %0, %1, off sc0\n\ts_waitcnt vmcnt(0)"
               : "=v"(v) : "v"(p) : "memory");
  return v;
}
// XCD-local 16B store into this XCD's L2
__device__ __forceinline__ void store16_l2(ull* p, u32x4 v) {
  asm volatile("global_store_dwordx4 %0, %1, off sc0" :: "v"(p), "v"(v) : "memory");
}

// Consumer poll: EXACT tag match only.
//  - ring tag == want            -> done (fast path, L2 hit)
//  - ring tag NEWER than want    -> the wanted value is provably complete on the
//    fabric (per-step vmcnt(0) drain at __syncthreads orders a producer's step-t
//    stores before any step-t+1 store issues) -> ONE fabric read, no spin.
//  - ring tag older              -> spin on ring, fabric fallback every 16 spins.
// Hard cap SPINCAP: break out regardless (wrong-but-terminating; validation
// catches it; the machine survives).
__device__ __forceinline__ u32x4 poll_ring(const ull* lp, const ull* fp, u32 want) {
  u32x4 v = cload16_l2(lp);
  int spins = 0;
  while (!(v.y == want && v.w == want)) {
    const bool newer = (v.y > want) || (v.w > want);
    if (newer || ((++spins & 15) == 0)) {
      v = cload16_dev(fp);
      if (v.y == want && v.w == want) break;
    } else {
      v = cload16_l2(lp);
    }
    if (spins > SPINCAP) break;
  }
  return v;
}

// Relay poll on the write-once fabric stream (tags only ever 0 -> want).
__device__ __forceinline__ u32x4 poll_fab(const ull* fp, u32 want) {
  u32x4 v = cload16_dev(fp);
  int spins = 0;
  while (v.y < want || v.w < want) {
    if (++spins > SPINCAP) break;
    v = cload16_dev(fp);
  }
  return v;
}

// ---------------- tiny helpers ----------------
__global__ void zero_f4(float4* __restrict__ p, size_t n4) {
  size_t i = (size_t)blockIdx.x * blockDim.x + threadIdx.x;
  size_t stride = (size_t)gridDim.x * blockDim.x;
  for (; i < n4; i += stride) p[i] = make_float4(0.f, 0.f, 0.f, 0.f);
}

__global__ void build_dec_tokens(const int* __restrict__ outputs, const int* __restrict__ sos,
                                 int* __restrict__ toks, int T) {
  int t = blockIdx.x * blockDim.x + threadIdx.x;
  if (t < T) toks[t] = (t == 0) ? sos[0] : outputs[t - 1];
}

// ---------------- f32 GEMM: C[M][N] = X[M][K] @ W[N][K]^T + b1 ----------------
__global__ __launch_bounds__(256) void gemm_xwt(
    const float* __restrict__ X, const float* __restrict__ W,
    const float* __restrict__ b1,
    float* __restrict__ C, int M, int N, int K)
{
  __shared__ float Xs[16][68];
  __shared__ float Ws[16][68];
  const int tid = threadIdx.x;
  const int tx = tid & 15;
  const int ty = tid >> 4;
  const int m0 = blockIdx.y * 64;
  const int n0 = blockIdx.x * 64;
  const int lr = tid >> 2;
  const int lc = (tid & 3) * 4;
  float acc[4][4] = {{0.f}};

  for (int k0 = 0; k0 < K; k0 += 16) {
    float4 xv = *(const float4*)(X + (size_t)(m0 + lr) * K + k0 + lc);
    float4 wv = make_float4(0.f, 0.f, 0.f, 0.f);
    int wr = n0 + lr;
    if (wr < N) wv = *(const float4*)(W + (size_t)wr * K + k0 + lc);
    __syncthreads();
    Xs[lc + 0][lr] = xv.x; Xs[lc + 1][lr] = xv.y; Xs[lc + 2][lr] = xv.z; Xs[lc + 3][lr] = xv.w;
    Ws[lc + 0][lr] = wv.x; Ws[lc + 1][lr] = wv.y; Ws[lc + 2][lr] = wv.z; Ws[lc + 3][lr] = wv.w;
    __syncthreads();
#pragma unroll
    for (int kk = 0; kk < 16; ++kk) {
      float4 a = *(const float4*)&Xs[kk][ty * 4];
      float4 b = *(const float4*)&Ws[kk][tx * 4];
      float av[4] = {a.x, a.y, a.z, a.w};
      float bv[4] = {b.x, b.y, b.z, b.w};
#pragma unroll
      for (int i = 0; i < 4; ++i)
#pragma unroll
        for (int j = 0; j < 4; ++j)
          acc[i][j] = fmaf(av[i], bv[j], acc[i][j]);
    }
  }
#pragma unroll
  for (int i = 0; i < 4; ++i) {
    int m = m0 + ty * 4 + i;
#pragma unroll
    for (int j = 0; j < 4; ++j) {
      int n = n0 + tx * 4 + j;
      if (n < N) C[(size_t)m * N + n] = acc[i][j] + (b1 ? b1[n] : 0.f);
    }
  }
}

// ---------------- fused 2-layer persistent LSTM: relay broadcast + pinned weights ----
// 256 WGs x 512 threads (1 WG/CU): wg<128 layer 0, wg>=128 layer 1 (1-step skew).
// 8 units/WG, 32 gate rows, 16 lanes/row, Wi+Wh rows pinned in VGPRs (asm "+v").
// Producers publish packed 8B {tag=t+1, h} to fabric streams s0/s1 (write-once).
// Per XCD: one L0 WG relays s0, one L1 WG relays s1 (CAS-elected, layer-matched
// so relay pace == consumer pace). Relays poll the FABRIC and republish into a
// 64-deep XCD-local L2 ring; everyone else uses poll_ring (exact-tag; stale-new
// => single guaranteed fabric read; hard spin caps everywhere).
__global__ __launch_bounds__(512, 2) void lstm2(
    const float* __restrict__ emb,  const int* __restrict__ toks,
    const float* __restrict__ Wi0,  const float* __restrict__ Wh0,
    const float* __restrict__ bi0,  const float* __restrict__ bh0,
    const float* __restrict__ Wi1,  const float* __restrict__ Wh1,
    const float* __restrict__ bi1,  const float* __restrict__ bh1,
    const float* __restrict__ h00,  const float* __restrict__ c00,
    const float* __restrict__ h01,  const float* __restrict__ c01,
    ull* __restrict__ s0, ull* __restrict__ s1,
    ull* __restrict__ ring,          // [8 xcd][2 stream][RDEPTH][1024] packed
    u32* __restrict__ elect,         // [8 xcd][2 stream], zeroed
    float* __restrict__ hf0, float* __restrict__ cf0,
    float* __restrict__ hf1, float* __restrict__ cf1,
    float* __restrict__ dec_out, int T)
{
  const int tid = threadIdx.x;
  const int wg  = blockIdx.x;
  const bool isL0 = (wg < 128);
  const int wgl = isL0 ? wg : wg - 128;

  const int lane16 = tid & 15;
  const int rloc = tid >> 4;            // 0..31 local gate row
  const int jloc = rloc & 7;
  const int gate = rloc >> 3;           // i,f,g,o
  const int grow = gate * HID + wgl * 8 + jloc;

  __shared__ float lds_x[2][HID];
  __shared__ float lds_h[HID];
  __shared__ float lds_g[32];
  __shared__ float lds_c[8];
  __shared__ u32 sh_xcd, sh_duty;

  // ---- per-XCD, layer-matched relay election (once per launch) ----
  if (tid == 0) {
    u32 xcc;
    asm volatile("s_getreg_b32 %0, hwreg(HW_REG_XCC_ID)" : "=s"(xcc));
    xcc &= 7;
    u32 duty = 0, exp = 0;
    if (isL0) {
      if (__hip_atomic_compare_exchange_strong(&elect[xcc * 2 + 0], &exp, 1u,
            __ATOMIC_RELAXED, __ATOMIC_RELAXED, __HIP_MEMORY_SCOPE_AGENT)) duty |= 1;
    } else {
      if (__hip_atomic_compare_exchange_strong(&elect[xcc * 2 + 1], &exp, 1u,
            __ATOMIC_RELAXED, __ATOMIC_RELAXED, __HIP_MEMORY_SCOPE_AGENT)) duty |= 2;
    }
    sh_xcd = xcc; sh_duty = duty;
  }

  // ---- weights -> registers, pinned ----
  const float* Wi = isL0 ? Wi0 : Wi1;
  const float* Wh = isL0 ? Wh0 : Wh1;
  const float breg = (isL0 ? (bi0[grow] + bh0[grow]) : (bi1[grow] + bh1[grow]));
  f32x4 Wir[16], Whr[16];
  {
    const f32x4* wi = (const f32x4*)(Wi + (size_t)grow * HID);
    const f32x4* wh = (const f32x4*)(Wh + (size_t)grow * HID);
#pragma unroll
    for (int i = 0; i < 16; ++i) {
      Wir[i] = wi[lane16 + i * 16];
      Whr[i] = wh[lane16 + i * 16];
    }
  }
#pragma unroll
  for (int i = 0; i < 16; ++i)        // opaque barrier: forbid re-load sinking
    asm volatile("" : "+v"(Wir[i]), "+v"(Whr[i]));

  {
    const float* hini = isL0 ? h00 : h01;
    const float* cini = isL0 ? c00 : c01;
    if (tid < 8) lds_c[tid] = cini[wgl * 8 + tid];
    if (tid < 256) ((float4*)lds_h)[tid] = ((const float4*)hini)[tid];
    if (isL0 && tid < 256) {
      int tok = toks[0];
      ((float4*)lds_x[0])[tid] = ((const float4*)(emb + (size_t)tok * HID))[tid];
    }
  }
  __syncthreads();
  const u32 duty = sh_duty;
  ull* ring0 = ring + ((size_t)sh_xcd * 2 + 0) * RDEPTH * HID;
  ull* ring1 = ring + ((size_t)sh_xcd * 2 + 1) * RDEPTH * HID;
  ull* s_mine = isL0 ? s0 : s1;

  for (int t = 0; t < T; ++t) {
    const int cur = t & 1;

    // ---- stage inputs ----
    if (isL0) {
      if (t > 0) {
        const int idx = t - 1; const u32 want = (u32)t;
        const ull* fp = s0 + (size_t)idx * HID + 2 * tid;
        ull* rp = ring0 + (size_t)(idx & (RDEPTH - 1)) * HID + 2 * tid;
        u32x4 v;
        if (duty & 1) { v = poll_fab(fp, want); store16_l2(rp, v); }
        else          { v = poll_ring(rp, fp, want); }
        lds_h[2 * tid]     = __uint_as_float(v.x);
        lds_h[2 * tid + 1] = __uint_as_float(v.z);
      }
    } else {
      {  // x = layer-0 h at step t (L1 never relays s0: poll_ring only)
        const int idx = t; const u32 want = (u32)(t + 1);
        const ull* fp = s0 + (size_t)idx * HID + 2 * tid;
        const ull* rp = ring0 + (size_t)(idx & (RDEPTH - 1)) * HID + 2 * tid;
        u32x4 v = poll_ring(rp, fp, want);
        lds_x[0][2 * tid]     = __uint_as_float(v.x);
        lds_x[0][2 * tid + 1] = __uint_as_float(v.z);
      }
      if (t > 0) {  // h = own h at step t-1
        const int idx = t - 1; const u32 want = (u32)t;
        const ull* fp = s1 + (size_t)idx * HID + 2 * tid;
        ull* rp = ring1 + (size_t)(idx & (RDEPTH - 1)) * HID + 2 * tid;
        u32x4 v;
        if (duty & 2) { v = poll_fab(fp, want); store16_l2(rp, v); }
        else          { v = poll_ring(rp, fp, want); }
        lds_h[2 * tid]     = __uint_as_float(v.x);
        lds_h[2 * tid + 1] = __uint_as_float(v.z);
      }
    }
    __syncthreads();

    // L0: prefetch x_{t+1} after the poll barrier (retires under compute)
    if (isL0 && tid < 256 && t + 1 < T) {
      int tok = toks[t + 1];
      ((float4*)lds_x[cur ^ 1])[tid] = ((const float4*)(emb + (size_t)tok * HID))[tid];
    }

    // ---- fused gate dot: Wi@x + Wh@h, 128 pinned-weight FMAs/thread ----
    const float* xbuf = isL0 ? lds_x[cur] : lds_x[0];
    float p0 = 0.f, p1 = 0.f, p2 = 0.f, p3 = 0.f;
#pragma unroll
    for (int i = 0; i < 16; ++i) {
      const float4 xv = *(const float4*)&xbuf[(lane16 << 2) + (i << 6)];
      p0 = fmaf(Wir[i].x, xv.x, p0);
      p1 = fmaf(Wir[i].y, xv.y, p1);
      p2 = fmaf(Wir[i].z, xv.z, p2);
      p3 = fmaf(Wir[i].w, xv.w, p3);
    }
#pragma unroll
    for (int i = 0; i < 16; ++i) {
      const float4 hv = *(const float4*)&lds_h[(lane16 << 2) + (i << 6)];
      p0 = fmaf(Whr[i].x, hv.x, p0);
      p1 = fmaf(Whr[i].y, hv.y, p1);
      p2 = fmaf(Whr[i].z, hv.z, p2);
      p3 = fmaf(Whr[i].w, hv.w, p3);
    }
    float sum = (p0 + p1) + (p2 + p3);
    sum += __shfl_xor(sum, 1);
    sum += __shfl_xor(sum, 2);
    sum += __shfl_xor(sum, 4);
    sum += __shfl_xor(sum, 8);
    if (lane16 == 0) lds_g[rloc] = sum + breg;
    __syncthreads();

    // ---- gate epilogue + packed publish to fabric ----
    if (tid < 8) {
      const float gi = lds_g[tid];
      const float gf = lds_g[8 + tid];
      const float gg = lds_g[16 + tid];
      const float go = lds_g[24 + tid];
      const float c = fsig_(gf) * lds_c[tid] + fsig_(gi) * ftanh_(gg);
      const float h = fsig_(go) * ftanh_(c);
      lds_c[tid] = c;
      const int col = wgl * 8 + tid;
      const ull pk = ((ull)(u32)(t + 1) << 32) | (ull)__float_as_uint(h);
      __hip_atomic_store(&s_mine[(size_t)t * HID + col], pk,
                         __ATOMIC_RELAXED, __HIP_MEMORY_SCOPE_AGENT);
      if (!isL0 && dec_out) dec_out[(size_t)t * HID + col] = h;
      if (t == T - 1) {
        if (isL0) { if (hf0) hf0[col] = h; if (cf0) cf0[col] = c; }
        else      { if (hf1) hf1[col] = h; if (cf1) cf1[col] = c; }
      }
    }
    // no trailing barrier: next step's post-poll barrier orders LDS reuse
  }

  // ---- s0 relay republishes the final step (in-loop pattern stops at T-2) ----
  if (isL0 && (duty & 1)) {
    const int idx = T - 1; const u32 want = (u32)T;
    const ull* fp = s0 + (size_t)idx * HID + 2 * tid;
    u32x4 v = poll_fab(fp, want);
    store16_l2(ring0 + (size_t)(idx & (RDEPTH - 1)) * HID + 2 * tid, v);
  }
}

// ---------------- launch ----------------
extern "C" void kernel_launch(void* const* d_in, const int* in_sizes, int n_in,
                              void* d_out, int out_size, void* d_ws, size_t ws_size,
                              hipStream_t stream) {
  const int*   inputs  = (const int*)d_in[0];
  const int*   outputs = (const int*)d_in[1];
  const int*   sos     = (const int*)d_in[2];
  const float* enc_emb = (const float*)d_in[3];
  const float* dec_emb = (const float*)d_in[4];
  const float* enc_Wih = (const float*)d_in[5];
  const float* enc_Whh = (const float*)d_in[6];
  const float* enc_bih = (const float*)d_in[7];
  const float* enc_bhh = (const float*)d_in[8];
  const float* dec_Wih = (const float*)d_in[9];
  const float* dec_Whh = (const float*)d_in[10];
  const float* dec_bih = (const float*)d_in[11];
  const float* dec_bhh = (const float*)d_in[12];
  const float* lin_W   = (const float*)d_in[13];
  const float* lin_b   = (const float*)d_in[14];

  float* out = (float*)d_out;
  // d_out scratch: 4 fabric streams (16 MB each), dead before logits GEMM.
  ull* s0e = (ull*)d_out;
  ull* s1e = s0e + 2097152;
  ull* s0d = s1e + 2097152;
  ull* s1d = s0d + 2097152;

  // ws carve: rings 2 x 8 MB, then control/small, then B2.
  char* ws = (char*)d_ws;
  ull*   ring_e  = (ull*)(ws + 0);                       // 8 MB  [8][2][64][1024]
  ull*   ring_d  = (ull*)(ws + ((size_t)8 << 20));       // 8 MB
  u32*   elect_e = (u32*)(ws + ((size_t)16 << 20));      // 64 B
  u32*   elect_d = (u32*)(ws + ((size_t)16 << 20) + 128);
  float* zerosv  = (float*)(ws + ((size_t)16 << 20) + 4096);
  float* hf0     = (float*)(ws + ((size_t)16 << 20) + 8192);
  float* cf0     = (float*)(ws + ((size_t)16 << 20) + 12288);
  float* hf1     = (float*)(ws + ((size_t)16 << 20) + 16384);
  float* cf1     = (float*)(ws + ((size_t)16 << 20) + 20480);
  int*   dtoks   = (int*)(ws + ((size_t)16 << 20) + 24576);
  float* B2      = (float*)(ws + ((size_t)17 << 20));    // 8 MB: dec_out

  const size_t WOFF = (size_t)GATES * HID;

  // zero fabric streams (64 MB in d_out) + rings/elect/zerosv (17 MB in ws);
  // every call: graph replays don't re-poison, protocol needs zero tags.
  zero_f4<<<2048, 256, 0, stream>>>((float4*)d_out, 4194304);
  zero_f4<<<2048, 256, 0, stream>>>((float4*)ws, ((size_t)17 << 20) / 16);
  build_dec_tokens<<<8, 256, 0, stream>>>(outputs, sos, dtoks, T_LEN);

  // encoder
  lstm2<<<256, 512, 0, stream>>>(
      enc_emb, inputs,
      enc_Wih, enc_Whh, enc_bih, enc_bhh,
      enc_Wih + WOFF, enc_Whh + WOFF, enc_bih + GATES, enc_bhh + GATES,
      zerosv, zerosv, zerosv, zerosv,
      s0e, s1e, ring_e, elect_e, hf0, cf0, hf1, cf1, nullptr, S_LEN);

  // decoder (init from encoder finals); layer-1 h also written plain to B2
  lstm2<<<256, 512, 0, stream>>>(
      dec_emb, dtoks,
      dec_Wih, dec_Whh, dec_bih, dec_bhh,
      dec_Wih + WOFF, dec_Whh + WOFF, dec_bih + GATES, dec_bhh + GATES,
      hf0, cf0, hf1, cf1,
      s0d, s1d, ring_d, elect_d, nullptr, nullptr, nullptr, nullptr, B2, T_LEN);

  // logits
  dim3 gemmV_grid((VOCAB + 63) / 64, T_LEN / 64);
  gemm_xwt<<<gemmV_grid, 256, 0, stream>>>(B2, lin_W, lin_b, out, T_LEN, VOCAB, HID);
}

// Round 9
// 16002.682 us; speedup vs baseline: 1.5622x; 1.5622x over previous
//
#include <hip/hip_runtime.h>
#include <hip/hip_bf16.h>
#include <math.h>

// ---------------- problem constants ----------------
#define S_LEN 2048
#define T_LEN 2048
#define HID   1024
#define GATES 4096
#define VOCAB 50257
#define L0_WGS 64            // 64 rows (16 units) per WG, 8 lanes/row
#define L1_WGS 128           // 32 rows (8 units) per WG, 16 lanes/row
#define NWG   (L0_WGS + L1_WGS)
#define SLOTS 512            // h slots per step: {u32 tag, 2xbf16}
#define SPINCAP 65536        // terminate (wrong-but-loud), never wedge

typedef unsigned int u32;
typedef unsigned long long ull;
typedef u32 u32x4 __attribute__((ext_vector_type(4)));

__device__ __forceinline__ float fsig_(float x)  { return 1.0f / (1.0f + __expf(-x)); }
__device__ __forceinline__ float ftanh_(float x) { float e = __expf(2.0f * x); return 1.0f - 2.0f / (e + 1.0f); }

// round-to-nearest-even f32 -> bf16 pair packed in u32 (a in low, b in high)
__device__ __forceinline__ u32 bf16pair(float a, float b) {
  u32 ua = __float_as_uint(a), ub = __float_as_uint(b);
  u32 ra = (ua + 0x7FFFu + ((ua >> 16) & 1u)) >> 16;
  u32 rb = (ub + 0x7FFFu + ((ub >> 16) & 1u)) >> 16;
  return ra | (rb << 16);
}

// device-coherent 16B load (bypass non-coherent L1/L2): two packed slots
__device__ __forceinline__ u32x4 cload16_dev(const ull* p) {
  u32x4 v;
  asm volatile("global_load_dwordx4 %0, %1, off sc0 sc1\n\ts_waitcnt vmcnt(0)"
               : "=v"(v) : "v"(p) : "memory");
  return v;
}

// spin until both slots' tags reach want (write-once stream, tags monotonic 0->t+1)
__device__ __forceinline__ u32x4 pollslots(const ull* p, u32 want) {
  u32x4 v = cload16_dev(p);
  int n = 0;
  while (v.y < want || v.w < want) {
    if (++n > SPINCAP) break;
    v = cload16_dev(p);
  }
  return v;
}

// ---------------- tiny helpers ----------------
__global__ void zero_f4(float4* __restrict__ p, size_t n4) {
  size_t i = (size_t)blockIdx.x * blockDim.x + threadIdx.x;
  size_t stride = (size_t)gridDim.x * blockDim.x;
  for (; i < n4; i += stride) p[i] = make_float4(0.f, 0.f, 0.f, 0.f);
}

__global__ void build_dec_tokens(const int* __restrict__ outputs, const int* __restrict__ sos,
                                 int* __restrict__ toks, int T) {
  int t = blockIdx.x * blockDim.x + threadIdx.x;
  if (t < T) toks[t] = (t == 0) ? sos[0] : outputs[t - 1];
}

__global__ void gather_rows(const float* __restrict__ emb, const int* __restrict__ toks,
                            float* __restrict__ out) {
  int row = blockIdx.x;
  int tok = toks[row];
  const float4* src = (const float4*)(emb + (size_t)tok * HID);
  float4* dst = (float4*)(out + (size_t)row * HID);
  dst[threadIdx.x] = src[threadIdx.x];
}

// ---------------- f32 GEMM: C[M][N] = X[M][K] @ W[N][K]^T + b1 + b2 ----------------
__global__ __launch_bounds__(256) void gemm_xwt(
    const float* __restrict__ X, const float* __restrict__ W,
    const float* __restrict__ b1, const float* __restrict__ b2,
    float* __restrict__ C, int M, int N, int K)
{
  __shared__ float Xs[16][68];
  __shared__ float Ws[16][68];
  const int tid = threadIdx.x;
  const int tx = tid & 15;
  const int ty = tid >> 4;
  const int m0 = blockIdx.y * 64;
  const int n0 = blockIdx.x * 64;
  const int lr = tid >> 2;
  const int lc = (tid & 3) * 4;
  float acc[4][4] = {{0.f}};

  for (int k0 = 0; k0 < K; k0 += 16) {
    float4 xv = *(const float4*)(X + (size_t)(m0 + lr) * K + k0 + lc);
    float4 wv = make_float4(0.f, 0.f, 0.f, 0.f);
    int wr = n0 + lr;
    if (wr < N) wv = *(const float4*)(W + (size_t)wr * K + k0 + lc);
    __syncthreads();
    Xs[lc + 0][lr] = xv.x; Xs[lc + 1][lr] = xv.y; Xs[lc + 2][lr] = xv.z; Xs[lc + 3][lr] = xv.w;
    Ws[lc + 0][lr] = wv.x; Ws[lc + 1][lr] = wv.y; Ws[lc + 2][lr] = wv.z; Ws[lc + 3][lr] = wv.w;
    __syncthreads();
#pragma unroll
    for (int kk = 0; kk < 16; ++kk) {
      float4 a = *(const float4*)&Xs[kk][ty * 4];
      float4 b = *(const float4*)&Ws[kk][tx * 4];
      float av[4] = {a.x, a.y, a.z, a.w};
      float bv[4] = {b.x, b.y, b.z, b.w};
#pragma unroll
      for (int i = 0; i < 4; ++i)
#pragma unroll
        for (int j = 0; j < 4; ++j)
          acc[i][j] = fmaf(av[i], bv[j], acc[i][j]);
    }
  }
#pragma unroll
  for (int i = 0; i < 4; ++i) {
    int m = m0 + ty * 4 + i;
#pragma unroll
    for (int j = 0; j < 4; ++j) {
      int n = n0 + tx * 4 + j;
      if (n < N) {
        float bias = 0.f;
        if (b1) bias += b1[n];
        if (b2) bias += b2[n];
        C[(size_t)m * N + n] = acc[i][j] + bias;
      }
    }
  }
}

// ---------------- fused 2-layer persistent LSTM: bf16 weights in LDS ----------------
// 192 WGs x 512 threads (1 WG/CU, LDS-bound). wg<64: layer 0 (A = Wi0@x+biases
// precomputed by GEMM; Wh0 slice bf16 in LDS). wg>=64: layer 1 (Wi1+Wh1 slices
// bf16 in LDS), 1-step pipeline skew. NO per-step global weight traffic.
// Exchange: write-once streams of packed 8B slots {tag=t+1 (hi32), 2xbf16 h
// (lo32)} -- 512 slots/step; consumers poll 256x16B coherent loads (4 units
// per load). Weights: thread-major LDS blocks (stride 67 u32 -> 2-way bank =
// free); h reads are float4 broadcasts (conflict-free).
__global__ __launch_bounds__(512, 1) void lstm2(
    const float* __restrict__ A,
    const float* __restrict__ Wh0,
    const float* __restrict__ Wi1,  const float* __restrict__ Wh1,
    const float* __restrict__ bi1,  const float* __restrict__ bh1,
    const float* __restrict__ h00,  const float* __restrict__ c00,
    const float* __restrict__ h01,  const float* __restrict__ c01,
    ull* __restrict__ s0, ull* __restrict__ s1,   // [T][SLOTS]
    float* __restrict__ hf0, float* __restrict__ cf0,
    float* __restrict__ hf1, float* __restrict__ cf1,
    float* __restrict__ dec_out, int T)
{
  const int tid = threadIdx.x;
  const int wg  = blockIdx.x;
  const bool isL0 = (wg < L0_WGS);

  __shared__ u32   wlds[512 * 67];   // 137 KB bf16 weight blocks (thread-major)
  __shared__ float lds_h[HID];
  __shared__ float lds_x[HID];
  __shared__ float lds_g[64];
  __shared__ float lds_c[16];

  if (isL0) {
    // ============ layer 0: 64 rows (16 units), 8 lanes/row ============
    const int l8   = tid & 7;
    const int rloc = tid >> 3;            // 0..63
    const int jloc = rloc & 15;
    const int gate = rloc >> 4;           // i,f,g,o
    const int grow = gate * HID + wg * 16 + jloc;

    // fill Wh0 slice -> LDS bf16 (one-time): thread owns cols {4*l8+32i+e}
    {
      const float4* wr = (const float4*)(Wh0 + (size_t)grow * HID);
#pragma unroll 4
      for (int i = 0; i < 32; ++i) {
        float4 w = wr[l8 + 8 * i];
        wlds[tid * 67 + 2 * i]     = bf16pair(w.x, w.y);
        wlds[tid * 67 + 2 * i + 1] = bf16pair(w.z, w.w);
      }
    }
    if (tid < 16) lds_c[tid] = c00[wg * 16 + tid];
    if (tid < 256) ((float4*)lds_h)[tid] = ((const float4*)h00)[tid];
    __syncthreads();

    float areg = A[grow];                 // step-0 preactivation (all lanes; lane0 uses)

    for (int t = 0; t < T; ++t) {
      if (t > 0) {
        if (tid < 256) {
          const ull* p = s0 + (size_t)(t - 1) * SLOTS + 2 * tid;
          u32x4 v = pollslots(p, (u32)t);
          lds_h[4 * tid + 0] = __uint_as_float(v.x << 16);
          lds_h[4 * tid + 1] = __uint_as_float(v.x & 0xFFFF0000u);
          lds_h[4 * tid + 2] = __uint_as_float(v.z << 16);
          lds_h[4 * tid + 3] = __uint_as_float(v.z & 0xFFFF0000u);
        }
        __syncthreads();
      }

      const float aval = areg;
      if (t + 1 < T) areg = A[(size_t)(t + 1) * GATES + grow];  // prefetch under compute

      float p0 = 0.f, p1 = 0.f, p2 = 0.f, p3 = 0.f;
      const int wb = tid * 67;
#pragma unroll
      for (int i = 0; i < 32; ++i) {
        const float4 hv = *(const float4*)&lds_h[4 * l8 + 32 * i];
        const u32 w0 = wlds[wb + 2 * i], w1 = wlds[wb + 2 * i + 1];
        p0 = fmaf(__uint_as_float(w0 << 16),         hv.x, p0);
        p1 = fmaf(__uint_as_float(w0 & 0xFFFF0000u), hv.y, p1);
        p2 = fmaf(__uint_as_float(w1 << 16),         hv.z, p2);
        p3 = fmaf(__uint_as_float(w1 & 0xFFFF0000u), hv.w, p3);
      }
      float sum = (p0 + p1) + (p2 + p3);
      sum += __shfl_xor(sum, 1);
      sum += __shfl_xor(sum, 2);
      sum += __shfl_xor(sum, 4);
      if (l8 == 0) lds_g[rloc] = sum + aval;
      __syncthreads();

      if (tid < 8) {                      // two units per thread -> one packed slot
        const int j0 = 2 * tid;
        const float c0v = fsig_(lds_g[16 + j0]) * lds_c[j0]
                        + fsig_(lds_g[j0]) * ftanh_(lds_g[32 + j0]);
        const float h0v = fsig_(lds_g[48 + j0]) * ftanh_(c0v);
        const float c1v = fsig_(lds_g[17 + j0]) * lds_c[j0 + 1]
                        + fsig_(lds_g[1 + j0]) * ftanh_(lds_g[33 + j0]);
        const float h1v = fsig_(lds_g[49 + j0]) * ftanh_(c1v);
        lds_c[j0] = c0v; lds_c[j0 + 1] = c1v;
        const ull pk = ((ull)(u32)(t + 1) << 32) | (ull)bf16pair(h0v, h1v);
        __hip_atomic_store(&s0[(size_t)t * SLOTS + wg * 8 + tid], pk,
                           __ATOMIC_RELAXED, __HIP_MEMORY_SCOPE_AGENT);
        if (t == T - 1 && hf0) {
          hf0[wg * 16 + j0] = h0v; hf0[wg * 16 + j0 + 1] = h1v;
          cf0[wg * 16 + j0] = c0v; cf0[wg * 16 + j0 + 1] = c1v;
        }
      }
      // no trailing barrier: next step's post-poll barrier orders lds_h reuse
    }
  } else {
    // ============ layer 1: 32 rows (8 units), 16 lanes/row, fused Wi+Wh ============
    const int wg1  = wg - L0_WGS;         // 0..127
    const int l16  = tid & 15;
    const int rloc = tid >> 4;            // 0..31
    const int jloc = rloc & 7;
    const int gate = rloc >> 3;
    const int grow = gate * HID + wg1 * 8 + jloc;

    // fill Wi1 (slots 0..31) + Wh1 (slots 32..63) -> LDS bf16: cols {4*l16+64i+e}
    {
      const float4* wi = (const float4*)(Wi1 + (size_t)grow * HID);
      const float4* wh = (const float4*)(Wh1 + (size_t)grow * HID);
#pragma unroll 4
      for (int i = 0; i < 16; ++i) {
        float4 a = wi[l16 + 16 * i];
        float4 b = wh[l16 + 16 * i];
        wlds[tid * 67 + 2 * i]          = bf16pair(a.x, a.y);
        wlds[tid * 67 + 2 * i + 1]      = bf16pair(a.z, a.w);
        wlds[tid * 67 + 32 + 2 * i]     = bf16pair(b.x, b.y);
        wlds[tid * 67 + 32 + 2 * i + 1] = bf16pair(b.z, b.w);
      }
    }
    const float breg = bi1[grow] + bh1[grow];
    if (tid < 8) lds_c[tid] = c01[wg1 * 8 + tid];
    if (tid < 256) ((float4*)lds_h)[tid] = ((const float4*)h01)[tid];
    __syncthreads();

    for (int t = 0; t < T; ++t) {
      if (tid < 256) {                    // x = layer-0 h at step t (want tag t+1)
        const ull* p = s0 + (size_t)t * SLOTS + 2 * tid;
        u32x4 v = pollslots(p, (u32)(t + 1));
        lds_x[4 * tid + 0] = __uint_as_float(v.x << 16);
        lds_x[4 * tid + 1] = __uint_as_float(v.x & 0xFFFF0000u);
        lds_x[4 * tid + 2] = __uint_as_float(v.z << 16);
        lds_x[4 * tid + 3] = __uint_as_float(v.z & 0xFFFF0000u);
      } else if (t > 0) {                 // h = own h at step t-1 (want tag t)
        const int u = tid - 256;
        const ull* p = s1 + (size_t)(t - 1) * SLOTS + 2 * u;
        u32x4 v = pollslots(p, (u32)t);
        lds_h[4 * u + 0] = __uint_as_float(v.x << 16);
        lds_h[4 * u + 1] = __uint_as_float(v.x & 0xFFFF0000u);
        lds_h[4 * u + 2] = __uint_as_float(v.z << 16);
        lds_h[4 * u + 3] = __uint_as_float(v.z & 0xFFFF0000u);
      }
      __syncthreads();

      float p0 = 0.f, p1 = 0.f, p2 = 0.f, p3 = 0.f;
      const int wb = tid * 67;
#pragma unroll
      for (int i = 0; i < 16; ++i) {
        const float4 xv = *(const float4*)&lds_x[4 * l16 + 64 * i];
        const u32 w0 = wlds[wb + 2 * i], w1 = wlds[wb + 2 * i + 1];
        p0 = fmaf(__uint_as_float(w0 << 16),         xv.x, p0);
        p1 = fmaf(__uint_as_float(w0 & 0xFFFF0000u), xv.y, p1);
        p2 = fmaf(__uint_as_float(w1 << 16),         xv.z, p2);
        p3 = fmaf(__uint_as_float(w1 & 0xFFFF0000u), xv.w, p3);
      }
#pragma unroll
      for (int i = 0; i < 16; ++i) {
        const float4 hv = *(const float4*)&lds_h[4 * l16 + 64 * i];
        const u32 w0 = wlds[wb + 32 + 2 * i], w1 = wlds[wb + 32 + 2 * i + 1];
        p0 = fmaf(__uint_as_float(w0 << 16),         hv.x, p0);
        p1 = fmaf(__uint_as_float(w0 & 0xFFFF0000u), hv.y, p1);
        p2 = fmaf(__uint_as_float(w1 << 16),         hv.z, p2);
        p3 = fmaf(__uint_as_float(w1 & 0xFFFF0000u), hv.w, p3);
      }
      float sum = (p0 + p1) + (p2 + p3);
      sum += __shfl_xor(sum, 1);
      sum += __shfl_xor(sum, 2);
      sum += __shfl_xor(sum, 4);
      sum += __shfl_xor(sum, 8);
      if (l16 == 0) lds_g[rloc] = sum + breg;
      __syncthreads();

      if (tid < 4) {                      // two units per thread -> one packed slot
        const int j0 = 2 * tid;
        const float c0v = fsig_(lds_g[8 + j0]) * lds_c[j0]
                        + fsig_(lds_g[j0]) * ftanh_(lds_g[16 + j0]);
        const float h0v = fsig_(lds_g[24 + j0]) * ftanh_(c0v);
        const float c1v = fsig_(lds_g[9 + j0]) * lds_c[j0 + 1]
                        + fsig_(lds_g[1 + j0]) * ftanh_(lds_g[17 + j0]);
        const float h1v = fsig_(lds_g[25 + j0]) * ftanh_(c1v);
        lds_c[j0] = c0v; lds_c[j0 + 1] = c1v;
        const ull pk = ((ull)(u32)(t + 1) << 32) | (ull)bf16pair(h0v, h1v);
        __hip_atomic_store(&s1[(size_t)t * SLOTS + wg1 * 4 + tid], pk,
                           __ATOMIC_RELAXED, __HIP_MEMORY_SCOPE_AGENT);
        if (dec_out) {
          dec_out[(size_t)t * HID + wg1 * 8 + j0]     = h0v;
          dec_out[(size_t)t * HID + wg1 * 8 + j0 + 1] = h1v;
        }
        if (t == T - 1 && hf1) {
          hf1[wg1 * 8 + j0] = h0v; hf1[wg1 * 8 + j0 + 1] = h1v;
          cf1[wg1 * 8 + j0] = c0v; cf1[wg1 * 8 + j0 + 1] = c1v;
        }
      }
    }
  }
}

// ---------------- launch ----------------
extern "C" void kernel_launch(void* const* d_in, const int* in_sizes, int n_in,
                              void* d_out, int out_size, void* d_ws, size_t ws_size,
                              hipStream_t stream) {
  const int*   inputs  = (const int*)d_in[0];
  const int*   outputs = (const int*)d_in[1];
  const int*   sos     = (const int*)d_in[2];
  const float* enc_emb = (const float*)d_in[3];
  const float* dec_emb = (const float*)d_in[4];
  const float* enc_Wih = (const float*)d_in[5];
  const float* enc_Whh = (const float*)d_in[6];
  const float* enc_bih = (const float*)d_in[7];
  const float* enc_bhh = (const float*)d_in[8];
  const float* dec_Wih = (const float*)d_in[9];
  const float* dec_Whh = (const float*)d_in[10];
  const float* dec_bih = (const float*)d_in[11];
  const float* dec_bhh = (const float*)d_in[12];
  const float* lin_W   = (const float*)d_in[13];
  const float* lin_b   = (const float*)d_in[14];

  float* out = (float*)d_out;
  // d_out scratch carve (all dead before the logits GEMM writes):
  //   A_enc @ 0 (8M f), A_dec @ 8M (8M f), 4 streams @ 16M f (8 MB each)
  float* A_enc = out;
  float* A_dec = out + 8388608;
  ull*   s0e   = (ull*)(out + 16777216);
  ull*   s1e   = s0e + (size_t)T_LEN * SLOTS;
  ull*   s0d   = s1e + (size_t)T_LEN * SLOTS;
  ull*   s1d   = s0d + (size_t)T_LEN * SLOTS;

  char* ws = (char*)d_ws;
  float* zerosv = (float*)(ws + 0);
  float* hf0    = (float*)(ws + 4096);
  float* cf0    = (float*)(ws + 8192);
  float* hf1    = (float*)(ws + 12288);
  float* cf1    = (float*)(ws + 16384);
  int*   dtoks  = (int*)(ws + 20480);
  float* B1 = (float*)(ws + ((size_t)1  << 20));  // 8 MB: enc embeddings
  float* B3 = (float*)(ws + ((size_t)10 << 20));  // 8 MB: dec embeddings
  float* B2 = (float*)(ws + ((size_t)19 << 20));  // 8 MB: dec_out (logits X)

  const size_t WOFF = (size_t)GATES * HID;

  // zero stream tags (32 MB in d_out) + zeros vector; every call (graph replay)
  zero_f4<<<2048, 256, 0, stream>>>((float4*)(out + 16777216), 2097152);
  zero_f4<<<1, 256, 0, stream>>>((float4*)zerosv, 256);
  build_dec_tokens<<<8, 256, 0, stream>>>(outputs, sos, dtoks, T_LEN);

  // embeddings + layer-0 preactivation GEMMs (teacher forcing: both precomputable)
  dim3 gemmA_grid(GATES / 64, S_LEN / 64);
  gather_rows<<<S_LEN, 256, 0, stream>>>(enc_emb, inputs, B1);
  gemm_xwt<<<gemmA_grid, 256, 0, stream>>>(B1, enc_Wih, enc_bih, enc_bhh, A_enc, S_LEN, GATES, HID);
  gather_rows<<<T_LEN, 256, 0, stream>>>(dec_emb, dtoks, B3);
  gemm_xwt<<<gemmA_grid, 256, 0, stream>>>(B3, dec_Wih, dec_bih, dec_bhh, A_dec, T_LEN, GATES, HID);

  // encoder: both layers pipelined, bf16 weights in LDS
  lstm2<<<NWG, 512, 0, stream>>>(
      A_enc, enc_Whh,
      enc_Wih + WOFF, enc_Whh + WOFF, enc_bih + GATES, enc_bhh + GATES,
      zerosv, zerosv, zerosv, zerosv,
      s0e, s1e, hf0, cf0, hf1, cf1, nullptr, S_LEN);

  // decoder (init from encoder finals); layer-1 h also written plain f32 to B2
  lstm2<<<NWG, 512, 0, stream>>>(
      A_dec, dec_Whh,
      dec_Wih + WOFF, dec_Whh + WOFF, dec_bih + GATES, dec_bhh + GATES,
      hf0, cf0, hf1, cf1,
      s0d, s1d, nullptr, nullptr, nullptr, nullptr, B2, T_LEN);

  // logits
  dim3 gemmV_grid((VOCAB + 63) / 64, T_LEN / 64);
  gemm_xwt<<<gemmV_grid, 256, 0, stream>>>(B2, lin_W, lin_b, nullptr, out, T_LEN, VOCAB, HID);
}

// Round 10
// 15933.142 us; speedup vs baseline: 1.5690x; 1.0044x over previous
//
#include <hip/hip_runtime.h>
#include <hip/hip_bf16.h>
#include <math.h>

// ---------------- problem constants ----------------
#define S_LEN 2048
#define T_LEN 2048
#define HID   1024
#define GATES 4096
#define VOCAB 50257
#define SPINCAP 262144       // terminate (wrong-but-loud), never wedge the chip

typedef unsigned int u32;
typedef unsigned long long ull;
typedef u32 u32x4 __attribute__((ext_vector_type(4)));
typedef float f32x4 __attribute__((ext_vector_type(4)));

__device__ __forceinline__ float fsig_(float x)  { return 1.0f / (1.0f + __expf(-x)); }
__device__ __forceinline__ float ftanh_(float x) { float e = __expf(2.0f * x); return 1.0f - 2.0f / (e + 1.0f); }

// coherent 16B load (bypasses non-coherent per-XCD L1/L2): two packed {tag,h} slots
__device__ __forceinline__ u32x4 cload16(const ull* p) {
  u32x4 v;
  asm volatile("global_load_dwordx4 %0, %1, off sc0 sc1\n\ts_waitcnt vmcnt(0)"
               : "=v"(v) : "v"(p) : "memory");
  return v;
}

// spin until both slots' tags reach want (write-once stream, tags monotonic 0->t+1)
__device__ __forceinline__ u32x4 pollslots(const ull* p, u32 want) {
  u32x4 v = cload16(p);
  int n = 0;
  while (v.y < want || v.w < want) {
    if (++n > SPINCAP) break;
    v = cload16(p);
  }
  return v;
}

// ---------------- tiny helpers ----------------
__global__ void zero_f4(float4* __restrict__ p, size_t n4) {
  size_t i = (size_t)blockIdx.x * blockDim.x + threadIdx.x;
  size_t stride = (size_t)gridDim.x * blockDim.x;
  for (; i < n4; i += stride) p[i] = make_float4(0.f, 0.f, 0.f, 0.f);
}

__global__ void build_dec_tokens(const int* __restrict__ outputs, const int* __restrict__ sos,
                                 int* __restrict__ toks, int T) {
  int t = blockIdx.x * blockDim.x + threadIdx.x;
  if (t < T) toks[t] = (t == 0) ? sos[0] : outputs[t - 1];
}

// ---------------- f32 GEMM: C[M][N] = X[M][K] @ W[N][K]^T + b1 ----------------
__global__ __launch_bounds__(256) void gemm_xwt(
    const float* __restrict__ X, const float* __restrict__ W,
    const float* __restrict__ b1,
    float* __restrict__ C, int M, int N, int K)
{
  __shared__ float Xs[16][68];
  __shared__ float Ws[16][68];
  const int tid = threadIdx.x;
  const int tx = tid & 15;
  const int ty = tid >> 4;
  const int m0 = blockIdx.y * 64;
  const int n0 = blockIdx.x * 64;
  const int lr = tid >> 2;
  const int lc = (tid & 3) * 4;
  float acc[4][4] = {{0.f}};

  for (int k0 = 0; k0 < K; k0 += 16) {
    float4 xv = *(const float4*)(X + (size_t)(m0 + lr) * K + k0 + lc);
    float4 wv = make_float4(0.f, 0.f, 0.f, 0.f);
    int wr = n0 + lr;
    if (wr < N) wv = *(const float4*)(W + (size_t)wr * K + k0 + lc);
    __syncthreads();
    Xs[lc + 0][lr] = xv.x; Xs[lc + 1][lr] = xv.y; Xs[lc + 2][lr] = xv.z; Xs[lc + 3][lr] = xv.w;
    Ws[lc + 0][lr] = wv.x; Ws[lc + 1][lr] = wv.y; Ws[lc + 2][lr] = wv.z; Ws[lc + 3][lr] = wv.w;
    __syncthreads();
#pragma unroll
    for (int kk = 0; kk < 16; ++kk) {
      float4 a = *(const float4*)&Xs[kk][ty * 4];
      float4 b = *(const float4*)&Ws[kk][tx * 4];
      float av[4] = {a.x, a.y, a.z, a.w};
      float bv[4] = {b.x, b.y, b.z, b.w};
#pragma unroll
      for (int i = 0; i < 4; ++i)
#pragma unroll
        for (int j = 0; j < 4; ++j)
          acc[i][j] = fmaf(av[i], bv[j], acc[i][j]);
    }
  }
#pragma unroll
  for (int i = 0; i < 4; ++i) {
    int m = m0 + ty * 4 + i;
#pragma unroll
    for (int j = 0; j < 4; ++j) {
      int n = n0 + tx * 4 + j;
      if (n < N) C[(size_t)m * N + n] = acc[i][j] + (b1 ? b1[n] : 0.f);
    }
  }
}

// ---------------- fused 2-layer persistent LSTM, VGPR-resident weights ----------------
// 256 WGs x 512 threads, 1 WG/CU. wg<128 layer 0 (x = embedding rows, LDS
// double-buffer prefetch); wg>=128 layer 1 (x = L0 h, 1-step skew). Both fuse
// Wi@x + Wh@h: 8 units/WG, 32 gate rows, 16 lanes/row, 128 weight f32/thread
// in VGPRs. __launch_bounds__(512,1) gives a 256-VGPR/thread budget -- the
// (512,2)=128-cap was why every prior "register weights" attempt silently
// spilled (VGPR_Count 84-88 across R1-R9). Exchange: R3/R5-proven write-once
// packed 8B slots {tag=t+1 (hi32), f32 h (lo32)}; consumers poll 2 adjacent
// slots with one coherent 16B load (per-8B tags detect torn halves).
__global__ __launch_bounds__(512, 1) void lstm2(
    const float* __restrict__ emb,  const int* __restrict__ toks,
    const float* __restrict__ Wi0,  const float* __restrict__ Wh0,
    const float* __restrict__ bi0,  const float* __restrict__ bh0,
    const float* __restrict__ Wi1,  const float* __restrict__ Wh1,
    const float* __restrict__ bi1,  const float* __restrict__ bh1,
    const float* __restrict__ h00,  const float* __restrict__ c00,
    const float* __restrict__ h01,  const float* __restrict__ c01,
    ull* __restrict__ s0, ull* __restrict__ s1,   // [T][1024] packed slots
    float* __restrict__ hf0, float* __restrict__ cf0,
    float* __restrict__ hf1, float* __restrict__ cf1,
    float* __restrict__ dec_out, int T)
{
  const int tid = threadIdx.x;
  const int wg  = blockIdx.x;
  const bool isL0 = (wg < 128);
  const int wgl = isL0 ? wg : wg - 128;

  const int lane16 = tid & 15;
  const int rloc = tid >> 4;            // 0..31 local gate row
  const int jloc = rloc & 7;            // unit within WG
  const int gate = rloc >> 3;           // 0=i 1=f 2=g 3=o
  const int grow = gate * HID + wgl * 8 + jloc;

  __shared__ float lds_x[2][HID];
  __shared__ float lds_h[HID];
  __shared__ float lds_g[32];
  __shared__ float lds_c[8];

  const float* Wi = isL0 ? Wi0 : Wi1;
  const float* Wh = isL0 ? Wh0 : Wh1;
  const float breg = (isL0 ? (bi0[grow] + bh0[grow]) : (bi1[grow] + bh1[grow]));

  // weight rows -> VGPRs: col block 4*(lane16 + 16*i); pinned (budget now allows)
  f32x4 Wir[16], Whr[16];
  {
    const f32x4* wi = (const f32x4*)(Wi + (size_t)grow * HID);
    const f32x4* wh = (const f32x4*)(Wh + (size_t)grow * HID);
#pragma unroll
    for (int i = 0; i < 16; ++i) {
      Wir[i] = wi[lane16 + i * 16];
      Whr[i] = wh[lane16 + i * 16];
    }
  }
#pragma unroll
  for (int i = 0; i < 16; ++i)
    asm volatile("" : "+v"(Wir[i]), "+v"(Whr[i]));

  {
    const float* hini = isL0 ? h00 : h01;
    const float* cini = isL0 ? c00 : c01;
    if (tid < 8) lds_c[tid] = cini[wgl * 8 + tid];
    if (tid < 256) ((float4*)lds_h)[tid] = ((const float4*)hini)[tid];
    if (isL0 && tid < 256) {           // stage x_0
      int tok = toks[0];
      ((float4*)lds_x[0])[tid] = ((const float4*)(emb + (size_t)tok * HID))[tid];
    }
  }
  __syncthreads();

  ull* s_mine = isL0 ? s0 : s1;

  for (int t = 0; t < T; ++t) {
    const int cur = t & 1;

    // ---- stage step inputs (polls on the critical path) ----
    if (isL0) {
      if (t > 0) {
        const ull* ph = s0 + (size_t)(t - 1) * HID + 2 * tid;
        u32x4 v = pollslots(ph, (u32)t);
        lds_h[2 * tid]     = __uint_as_float(v.x);
        lds_h[2 * tid + 1] = __uint_as_float(v.z);
      }
    } else {
      {
        const ull* px = s0 + (size_t)t * HID + 2 * tid;
        u32x4 v = pollslots(px, (u32)(t + 1));
        lds_x[0][2 * tid]     = __uint_as_float(v.x);
        lds_x[0][2 * tid + 1] = __uint_as_float(v.z);
      }
      if (t > 0) {
        const ull* ph = s1 + (size_t)(t - 1) * HID + 2 * tid;
        u32x4 v = pollslots(ph, (u32)t);
        lds_h[2 * tid]     = __uint_as_float(v.x);
        lds_h[2 * tid + 1] = __uint_as_float(v.z);
      }
    }
    __syncthreads();

    // L0: prefetch x_{t+1} after the poll barrier (retires under compute)
    if (isL0 && tid < 256 && t + 1 < T) {
      int tok = toks[t + 1];
      ((float4*)lds_x[cur ^ 1])[tid] = ((const float4*)(emb + (size_t)tok * HID))[tid];
    }

    // ---- fused gate dot: Wi@x + Wh@h, 128 VGPR-weight FMAs/thread ----
    const float* xbuf = isL0 ? lds_x[cur] : lds_x[0];
    float p0 = 0.f, p1 = 0.f, p2 = 0.f, p3 = 0.f;
#pragma unroll
    for (int i = 0; i < 16; ++i) {
      const float4 xv = *(const float4*)&xbuf[(lane16 << 2) + (i << 6)];
      p0 = fmaf(Wir[i].x, xv.x, p0);
      p1 = fmaf(Wir[i].y, xv.y, p1);
      p2 = fmaf(Wir[i].z, xv.z, p2);
      p3 = fmaf(Wir[i].w, xv.w, p3);
    }
#pragma unroll
    for (int i = 0; i < 16; ++i) {
      const float4 hv = *(const float4*)&lds_h[(lane16 << 2) + (i << 6)];
      p0 = fmaf(Whr[i].x, hv.x, p0);
      p1 = fmaf(Whr[i].y, hv.y, p1);
      p2 = fmaf(Whr[i].z, hv.z, p2);
      p3 = fmaf(Whr[i].w, hv.w, p3);
    }
    float sum = (p0 + p1) + (p2 + p3);
    sum += __shfl_xor(sum, 1);
    sum += __shfl_xor(sum, 2);
    sum += __shfl_xor(sum, 4);
    sum += __shfl_xor(sum, 8);
    if (lane16 == 0) lds_g[rloc] = sum + breg;
    __syncthreads();

    // ---- gate epilogue + packed publish ----
    if (tid < 8) {
      const float gi = lds_g[tid];
      const float gf = lds_g[8 + tid];
      const float gg = lds_g[16 + tid];
      const float go = lds_g[24 + tid];
      const float c = fsig_(gf) * lds_c[tid] + fsig_(gi) * ftanh_(gg);
      const float h = fsig_(go) * ftanh_(c);
      lds_c[tid] = c;
      const int col = wgl * 8 + tid;
      const ull pk = ((ull)(u32)(t + 1) << 32) | (ull)__float_as_uint(h);
      __hip_atomic_store(&s_mine[(size_t)t * HID + col], pk,
                         __ATOMIC_RELAXED, __HIP_MEMORY_SCOPE_AGENT);
      if (!isL0 && dec_out) dec_out[(size_t)t * HID + col] = h;
      if (t == T - 1) {
        if (isL0) { if (hf0) hf0[col] = h; if (cf0) cf0[col] = c; }
        else      { if (hf1) hf1[col] = h; if (cf1) cf1[col] = c; }
      }
    }
    // no trailing barrier: next step's post-poll barrier orders LDS reuse
  }
}

// ---------------- launch ----------------
extern "C" void kernel_launch(void* const* d_in, const int* in_sizes, int n_in,
                              void* d_out, int out_size, void* d_ws, size_t ws_size,
                              hipStream_t stream) {
  const int*   inputs  = (const int*)d_in[0];
  const int*   outputs = (const int*)d_in[1];
  const int*   sos     = (const int*)d_in[2];
  const float* enc_emb = (const float*)d_in[3];
  const float* dec_emb = (const float*)d_in[4];
  const float* enc_Wih = (const float*)d_in[5];
  const float* enc_Whh = (const float*)d_in[6];
  const float* enc_bih = (const float*)d_in[7];
  const float* enc_bhh = (const float*)d_in[8];
  const float* dec_Wih = (const float*)d_in[9];
  const float* dec_Whh = (const float*)d_in[10];
  const float* dec_bih = (const float*)d_in[11];
  const float* dec_bhh = (const float*)d_in[12];
  const float* lin_W   = (const float*)d_in[13];
  const float* lin_b   = (const float*)d_in[14];

  float* out = (float*)d_out;
  // d_out scratch: 4 packed streams (16 MB each), all dead before logits GEMM.
  ull* s0e = (ull*)d_out;
  ull* s1e = s0e + 2097152;
  ull* s0d = s1e + 2097152;
  ull* s1d = s0d + 2097152;

  char* ws = (char*)d_ws;
  float* zerosv = (float*)(ws + 0);
  float* hf0    = (float*)(ws + 4096);
  float* cf0    = (float*)(ws + 8192);
  float* hf1    = (float*)(ws + 12288);
  float* cf1    = (float*)(ws + 16384);
  int*   dtoks  = (int*)(ws + 20480);
  float* B2     = (float*)(ws + ((size_t)1 << 20));   // 8 MB: dec_out (logits X)

  const size_t WOFF = (size_t)GATES * HID;

  // zero stream tags (64 MB in d_out) + zeros vector; every call (graph replay)
  zero_f4<<<2048, 256, 0, stream>>>((float4*)d_out, 4194304);
  zero_f4<<<1, 256, 0, stream>>>((float4*)zerosv, 256);
  build_dec_tokens<<<8, 256, 0, stream>>>(outputs, sos, dtoks, T_LEN);

  // encoder: both layers, fused Wi@x, layer-pipelined
  lstm2<<<256, 512, 0, stream>>>(
      enc_emb, inputs,
      enc_Wih, enc_Whh, enc_bih, enc_bhh,
      enc_Wih + WOFF, enc_Whh + WOFF, enc_bih + GATES, enc_bhh + GATES,
      zerosv, zerosv, zerosv, zerosv,
      s0e, s1e, hf0, cf0, hf1, cf1, nullptr, S_LEN);

  // decoder: init from encoder finals; layer-1 h also written plain to B2
  lstm2<<<256, 512, 0, stream>>>(
      dec_emb, dtoks,
      dec_Wih, dec_Whh, dec_bih, dec_bhh,
      dec_Wih + WOFF, dec_Whh + WOFF, dec_bih + GATES, dec_bhh + GATES,
      hf0, cf0, hf1, cf1,
      s0d, s1d, nullptr, nullptr, nullptr, nullptr, B2, T_LEN);

  // logits
  dim3 gemmV_grid((VOCAB + 63) / 64, T_LEN / 64);
  gemm_xwt<<<gemmV_grid, 256, 0, stream>>>(B2, lin_W, lin_b, out, T_LEN, VOCAB, HID);
}